// Round 9
// baseline (70501.007 us; speedup 1.0000x reference)
//
#include <hip/hip_runtime.h>
#include <hip/hip_bf16.h>
#include <stdint.h>

// LSTM: T=2048, B=64, I=256, H=256, gates 4H=1024, K = I+H = 512.
// BATCH-LOCAL design: 4 WGs x 1024 threads (16 waves). WG bid owns batch
// rows [16*bid,+16) and runs all 2048 steps with ZERO cross-CU traffic:
// a full weight copy (512x1024 bf16 = 1 MB) lives in the CU's VGPR file
// (256 regs/lane x 16 waves). Wave w owns h-cols [16w,+16) = gate rows
// {256g+16w+n}: acc tile per gate => i,f,g,o are LANE-LOCAL (no shuffles),
// c in 4 VGPRs/lane. h round-trips through double-buffered, XOR-swizzled
// LDS; one __syncthreads per step is the only synchronization.

#define T_STEPS 2048

typedef float f32x4 __attribute__((ext_vector_type(4)));
typedef short bf16x8 __attribute__((ext_vector_type(8)));

__device__ __forceinline__ unsigned short tobf(float f) {
    __hip_bfloat16 h = __float2bfloat16(f);
    return *reinterpret_cast<unsigned short*>(&h);
}

__device__ __forceinline__ bf16x8 pack8(f32x4 a, f32x4 b) {
    bf16x8 r;
    r[0] = (short)tobf(a[0]); r[1] = (short)tobf(a[1]);
    r[2] = (short)tobf(a[2]); r[3] = (short)tobf(a[3]);
    r[4] = (short)tobf(b[0]); r[5] = (short)tobf(b[1]);
    r[6] = (short)tobf(b[2]); r[7] = (short)tobf(b[3]);
    return r;
}

__device__ __forceinline__ float fast_sig(float x) {
    float e = __builtin_amdgcn_exp2f(-1.4426950408889634f * x);
    return __builtin_amdgcn_rcpf(1.0f + e);
}
__device__ __forceinline__ float fast_tanh(float x) {
    float xc = fminf(fmaxf(x, -15.0f), 15.0f);
    float e = __builtin_amdgcn_exp2f(2.8853900817779268f * xc);
    return (e - 1.0f) * __builtin_amdgcn_rcpf(e + 1.0f);
}

__global__ __launch_bounds__(1024, 1)
void lstm_batchlocal(const float* __restrict__ x,
                     const float* __restrict__ W_ih,
                     const float* __restrict__ W_hh,
                     const float* __restrict__ b_ih,
                     const float* __restrict__ b_hh,
                     float* __restrict__ out)
{
    const int bid = blockIdx.x;          // 0..3: batch rows [16*bid, +16)
    const int tid = threadIdx.x;         // 0..1023
    const int w   = tid >> 6;            // wave 0..15: h-cols [16w, +16)
    const int l   = tid & 63;
    const int l15 = l & 15;
    const int lk  = l >> 4;              // 0..3

    // double-buffered h tile [16 rows][256 cols] bf16, XOR-swizzled
    __shared__ __align__(16) unsigned short hlds[2][16 * 256];

    // zero both buffers (h_0 = 0)
    {
        uint32_t* z = (uint32_t*)hlds;
        for (int i = tid; i < 2 * 16 * 256 / 2; i += 1024) z[i] = 0u;
    }

    // ---- resident weights: wf[gate][ktile], B-frag n = l15, k = kt*32+lk*8+j ----
    bf16x8 wf[4][16];
    float bias[4];
#pragma unroll
    for (int g = 0; g < 4; ++g) {
        const int grow = 256 * g + 16 * w + l15;
#pragma unroll
        for (int kt = 0; kt < 16; ++kt) {
            const float* src = (kt < 8)
                ? (W_ih + (size_t)grow * 256 + kt * 32 + lk * 8)
                : (W_hh + (size_t)grow * 256 + (kt - 8) * 32 + lk * 8);
            wf[g][kt] = pack8(*(const f32x4*)(src), *(const f32x4*)(src + 4));
        }
        bias[g] = b_ih[grow] + b_hh[grow];
    }

    // A-fragment source: batch row 16*bid + l15, k = kt*32 + lk*8 + j
    const float* xbase = x + ((size_t)(16 * bid + l15)) * 256 + lk * 8;

    float cst[4] = {0.f, 0.f, 0.f, 0.f};   // c for rows 4*lk+r, col 16*w+l15

    // prefetch x_0
    f32x4 xs[16];
#pragma unroll
    for (int kt = 0; kt < 8; ++kt) {
        xs[2 * kt]     = *(const f32x4*)(xbase + kt * 32);
        xs[2 * kt + 1] = *(const f32x4*)(xbase + kt * 32 + 4);
    }

    for (int s = 0; s < T_STEPS; ++s) {
        // ---- convert staged x_s; x-half MFMAs (no h dependency) ----
        bf16x8 af[8];
#pragma unroll
        for (int kt = 0; kt < 8; ++kt) af[kt] = pack8(xs[2 * kt], xs[2 * kt + 1]);

        f32x4 acc[4] = {{0.f,0.f,0.f,0.f},{0.f,0.f,0.f,0.f},
                        {0.f,0.f,0.f,0.f},{0.f,0.f,0.f,0.f}};
#pragma unroll
        for (int kt = 0; kt < 8; ++kt)
#pragma unroll
            for (int g = 0; g < 4; ++g)
                acc[g] = __builtin_amdgcn_mfma_f32_16x16x32_bf16(af[kt], wf[g][kt], acc[g], 0, 0, 0);

        // ---- prefetch x_{s+1} (in flight across barrier + h phase) ----
        if (s + 1 < T_STEPS) {
            const float* xp = xbase + (size_t)(s + 1) * 16384;
#pragma unroll
            for (int kt = 0; kt < 8; ++kt) {
                xs[2 * kt]     = *(const f32x4*)(xp + kt * 32);
                xs[2 * kt + 1] = *(const f32x4*)(xp + kt * 32 + 4);
            }
        }

        __syncthreads();   // h_{s} writes (prev step) visible to all waves

        // ---- h-half MFMAs: A-frags from swizzled LDS ----
        const char* hrd = (const char*)&hlds[s & 1][0];
#pragma unroll
        for (int kt = 0; kt < 8; ++kt) {
            const int boff = (l15 * 512 + (kt * 32 + lk * 8) * 2) ^ ((l15 & 7) << 4);
            bf16x8 hf = *(const bf16x8*)(hrd + boff);
#pragma unroll
            for (int g = 0; g < 4; ++g)
                acc[g] = __builtin_amdgcn_mfma_f32_16x16x32_bf16(hf, wf[g][8 + kt], acc[g], 0, 0, 0);
        }

        // ---- epilogue: i,f,g,o lane-local; update c; write h to LDS ----
        char* hwr = (char*)&hlds[(s + 1) & 1][0];
#pragma unroll
        for (int r = 0; r < 4; ++r) {
            const int mr = 4 * lk + r;                  // batch row (local)
            float iv = acc[0][r] + bias[0];
            float fv = acc[1][r] + bias[1];
            float gv = acc[2][r] + bias[2];
            float ov = acc[3][r] + bias[3];
            float cn = fast_sig(fv) * cst[r] + fast_sig(iv) * fast_tanh(gv);
            cst[r] = cn;
            float hv = fast_sig(ov) * fast_tanh(cn);

            const int col  = 16 * w + l15;
            const int boff = (mr * 512 + col * 2) ^ ((mr & 7) << 4);
            *(unsigned short*)(hwr + boff) = tobf(hv);

            if (s == T_STEPS - 1)
                out[(size_t)(16 * bid + mr) * 256 + col] = hv;
        }
        // next iteration's __syncthreads guards these writes before reads
    }
}

extern "C" void kernel_launch(void* const* d_in, const int* in_sizes, int n_in,
                              void* d_out, int out_size, void* d_ws, size_t ws_size,
                              hipStream_t stream) {
    const float* x    = (const float*)d_in[0];
    const float* W_ih = (const float*)d_in[1];
    const float* W_hh = (const float*)d_in[2];
    const float* b_ih = (const float*)d_in[3];
    const float* b_hh = (const float*)d_in[4];
    float* out = (float*)d_out;

    lstm_batchlocal<<<dim3(4), dim3(1024), 0, stream>>>(x, W_ih, W_hh,
                                                        b_ih, b_hh, out);
}

// Round 12
// 38717.218 us; speedup vs baseline: 1.8209x; 1.8209x over previous
//
#include <hip/hip_runtime.h>
#include <hip/hip_bf16.h>
#include <stdint.h>

// LSTM: T=2048, B=64, I=256, H=256, gates 4H=1024, K = I+H = 512.
// 32 WGs x 256 threads = 128 independent waves. Wave (wg,wv) owns batch
// rows [16wv,+16) x h-cols [8wg,+8). Weights resident in VGPRs (128/lane).
// SINGLE-RTT sync: h stored as u32 words (bf16<<16 | step_tag) into two
// tagged buffers: buf0 = d_ws (64KB), buf1 = d_out (64KB, reused as scratch).
// Consumers poll the data words themselves (u64 relaxed atomic loads);
// producer stores are fire-and-forget. Tag completeness of step s proves all
// step-(s-1) reads retired => 2 buffers suffice with NO reuse gate.
// Spin loops carry a ~16M-sleep budget: a (theoretically impossible)
// deadlock degrades to a fast wrong-answer instead of a 600s timeout.
// End: tiny flag barrier per wv-cohort gates the f32 final writes into d_out.

#define T_STEPS 2048
#define NWG 32

typedef float f32x4 __attribute__((ext_vector_type(4)));
typedef short bf16x8 __attribute__((ext_vector_type(8)));
typedef uint32_t u32x4 __attribute__((ext_vector_type(4)));

__device__ __forceinline__ unsigned short tobf(float f) {
    __hip_bfloat16 h = __float2bfloat16(f);
    return *reinterpret_cast<unsigned short*>(&h);
}

__device__ __forceinline__ bf16x8 pack8(f32x4 a, f32x4 b) {
    bf16x8 r;
    r[0] = (short)tobf(a[0]); r[1] = (short)tobf(a[1]);
    r[2] = (short)tobf(a[2]); r[3] = (short)tobf(a[3]);
    r[4] = (short)tobf(b[0]); r[5] = (short)tobf(b[1]);
    r[6] = (short)tobf(b[2]); r[7] = (short)tobf(b[3]);
    return r;
}

__device__ __forceinline__ float fast_sig(float x) {
    float e = __builtin_amdgcn_exp2f(-1.4426950408889634f * x);
    return __builtin_amdgcn_rcpf(1.0f + e);
}
__device__ __forceinline__ float fast_tanh(float x) {
    float xc = fminf(fmaxf(x, -15.0f), 15.0f);
    float e = __builtin_amdgcn_exp2f(2.8853900817779268f * xc);
    return (e - 1.0f) * __builtin_amdgcn_rcpf(e + 1.0f);
}

__global__ __launch_bounds__(256, 1)
void lstm_tagged(const float* __restrict__ x,
                 const float* __restrict__ W_ih,
                 const float* __restrict__ W_hh,
                 const float* __restrict__ b_ih,
                 const float* __restrict__ b_hh,
                 uint32_t* __restrict__ buf0,   // d_ws: [64][256] u32 tagged
                 uint32_t* __restrict__ buf1,   // d_out: [64][256] u32 tagged / f32 finals
                 uint32_t* __restrict__ flags)  // [4][32] u32 end-barrier
{
    const int wg   = blockIdx.x;     // 0..31
    const int tid  = threadIdx.x;    // 0..255
    const int wv   = tid >> 6;       // wave 0..3 = batch group
    const int l    = tid & 63;
    const int l15  = l & 15;
    const int lk   = l >> 4;         // 0..3
    const int gate = l15 >> 2;       // 0:i 1:f 2:g 3:o
    const int jj   = l15 & 3;

    int budget = 1 << 24;            // total spin-sleep budget (deadlock escape)

    // ---- resident weight fragments: 2 N-groups x 16 ktiles of K=32 ----
    bf16x8 wf[2][16];
    float bias[2];
#pragma unroll
    for (int p = 0; p < 2; ++p) {
        const int grow = 256 * gate + 8 * wg + 4 * p + jj;
#pragma unroll
        for (int kt = 0; kt < 16; ++kt) {
            const float* src = (kt < 8)
                ? (W_ih + (size_t)grow * 256 + kt * 32 + lk * 8)
                : (W_hh + (size_t)grow * 256 + (kt - 8) * 32 + lk * 8);
            wf[p][kt] = pack8(*(const f32x4*)(src), *(const f32x4*)(src + 4));
        }
        bias[p] = b_ih[grow] + b_hh[grow];
    }

    const int arow = 16 * wv + l15;            // batch row for A fragments
    const float* xbase = x + (size_t)arow * 256 + lk * 8;

    float cst[2][4] = {{0.f,0.f,0.f,0.f},{0.f,0.f,0.f,0.f}};

    // ---- prologue: x_0 packed -> x-half(0) in aA/aB; then stage x_1 ----
    bf16x8 xsp[8];
#pragma unroll
    for (int kt = 0; kt < 8; ++kt)
        xsp[kt] = pack8(*(const f32x4*)(xbase + kt * 32),
                        *(const f32x4*)(xbase + kt * 32 + 4));

    f32x4 aA[2] = {{0.f,0.f,0.f,0.f},{0.f,0.f,0.f,0.f}};
    f32x4 aB[2] = {{0.f,0.f,0.f,0.f},{0.f,0.f,0.f,0.f}};
#pragma unroll
    for (int kt = 0; kt < 8; kt += 2)
#pragma unroll
        for (int p = 0; p < 2; ++p) {
            aA[p] = __builtin_amdgcn_mfma_f32_16x16x32_bf16(xsp[kt],     wf[p][kt],     aA[p], 0, 0, 0);
            aB[p] = __builtin_amdgcn_mfma_f32_16x16x32_bf16(xsp[kt + 1], wf[p][kt + 1], aB[p], 0, 0, 0);
        }
#pragma unroll
    for (int kt = 0; kt < 8; ++kt)
        xsp[kt] = pack8(*(const f32x4*)(xbase + 16384 + kt * 32),
                        *(const f32x4*)(xbase + 16384 + kt * 32 + 4));

    for (int s = 0; s < T_STEPS; ++s) {
        // ---- issue tagged h_s loads (u64 relaxed atomics, MALL) ----
        const uint32_t* rb = (s & 1) ? buf1 : buf0;
        const unsigned long long* hb64 =
            (const unsigned long long*)(rb + (size_t)arow * 256) + 4 * lk;
        unsigned long long hq[32];
#pragma unroll
        for (int kh = 0; kh < 8; ++kh)
#pragma unroll
            for (int i = 0; i < 4; ++i)
                hq[4 * kh + i] = __hip_atomic_load(hb64 + 16 * kh + i,
                                                   __ATOMIC_RELAXED, __HIP_MEMORY_SCOPE_AGENT);

        // ---- x-half(s+1) into acc2 while loads are in flight ----
        f32x4 aA2[2] = {{0.f,0.f,0.f,0.f},{0.f,0.f,0.f,0.f}};
        f32x4 aB2[2] = {{0.f,0.f,0.f,0.f},{0.f,0.f,0.f,0.f}};
        if (s + 1 < T_STEPS) {
#pragma unroll
            for (int kt = 0; kt < 8; kt += 2)
#pragma unroll
                for (int p = 0; p < 2; ++p) {
                    aA2[p] = __builtin_amdgcn_mfma_f32_16x16x32_bf16(xsp[kt],     wf[p][kt],     aA2[p], 0, 0, 0);
                    aB2[p] = __builtin_amdgcn_mfma_f32_16x16x32_bf16(xsp[kt + 1], wf[p][kt + 1], aB2[p], 0, 0, 0);
                }
        }
        __builtin_amdgcn_sched_barrier(0);

        // ---- tag check: every u32 word must carry tag s; retry if stale ----
        const unsigned long long tagpair =
            (unsigned long long)(uint32_t)s * 0x0000000100000001ull;
        const unsigned long long tmask = 0x0000FFFF0000FFFFull;
        while (true) {
            unsigned long long bad = 0;
#pragma unroll
            for (int i = 0; i < 32; ++i) bad |= (hq[i] ^ tagpair) & tmask;
            if (__all(bad == 0ull)) break;
            if (--budget < 0) break;           // deadlock escape (never in normal run)
            __builtin_amdgcn_s_sleep(1);
#pragma unroll
            for (int kh = 0; kh < 8; ++kh)
#pragma unroll
                for (int i = 0; i < 4; ++i)
                    hq[4 * kh + i] = __hip_atomic_load(hb64 + 16 * kh + i,
                                                       __ATOMIC_RELAXED, __HIP_MEMORY_SCOPE_AGENT);
        }

        // ---- unpack payloads -> h fragments; h-half MFMAs ----
#pragma unroll
        for (int kh = 0; kh < 8; ++kh) {
            u32x4 t;
#pragma unroll
            for (int i = 0; i < 4; ++i) {
                unsigned long long q = hq[4 * kh + i];
                t[i] = (((uint32_t)q) >> 16) | ((uint32_t)(q >> 32) & 0xFFFF0000u);
            }
            bf16x8 hf = __builtin_bit_cast(bf16x8, t);
#pragma unroll
            for (int p = 0; p < 2; ++p) {
                if (kh & 1) aB[p] = __builtin_amdgcn_mfma_f32_16x16x32_bf16(hf, wf[p][8 + kh], aB[p], 0, 0, 0);
                else        aA[p] = __builtin_amdgcn_mfma_f32_16x16x32_bf16(hf, wf[p][8 + kh], aA[p], 0, 0, 0);
            }
        }

        // ---- epilogue: gather i/f/g/o, update c, h ----
        const int orow0 = 16 * wv + 4 * lk;
        float hv[2][4];
#pragma unroll
        for (int p = 0; p < 2; ++p) {
#pragma unroll
            for (int r = 0; r < 4; ++r) {
                float vo  = aA[p][r] + aB[p][r] + bias[p];
                float v4  = __shfl_xor(vo, 4);
                float v8  = __shfl_xor(vo, 8);
                float v12 = __shfl_xor(vo, 12);
                float iv = (gate == 0) ? vo : ((gate == 1) ? v4 : ((gate == 2) ? v8 : v12));
                float fv = (gate == 1) ? vo : ((gate == 0) ? v4 : ((gate == 3) ? v8 : v12));
                float gv = (gate == 2) ? vo : ((gate == 3) ? v4 : ((gate == 0) ? v8 : v12));
                float ov = (gate == 3) ? vo : ((gate == 2) ? v4 : ((gate == 1) ? v8 : v12));
                float cn = fast_sig(fv) * cst[p][r] + fast_sig(iv) * fast_tanh(gv);
                cst[p][r] = cn;
                hv[p][r] = fast_sig(ov) * fast_tanh(cn);
            }
        }

        // ---- store tagged h_{s+1} (fire-and-forget) ----
        if (s + 1 < T_STEPS) {
            uint32_t* wb = ((s + 1) & 1) ? buf1 : buf0;
            const uint32_t tago = (uint32_t)(s + 1);
#pragma unroll
            for (int p = 0; p < 2; ++p)
#pragma unroll
                for (int r = 0; r < 4; ++r)
                    if ((l & 12) == 0) {   // gate==0 lanes: 16 lanes cover the tile
                        uint32_t word = ((uint32_t)tobf(hv[p][r]) << 16) | tago;
                        __hip_atomic_store(wb + (size_t)(orow0 + r) * 256
                                               + 8 * wg + 4 * p + jj,
                                           word, __ATOMIC_RELAXED, __HIP_MEMORY_SCOPE_AGENT);
                    }
        }

        // ---- rotate accumulators; prefetch x_{s+2} ----
#pragma unroll
        for (int p = 0; p < 2; ++p) { aA[p] = aA2[p]; aB[p] = aB2[p]; }
        if (s + 2 < T_STEPS) {
            const float* xp = xbase + (size_t)(s + 2) * 16384;
#pragma unroll
            for (int kt = 0; kt < 8; ++kt)
                xsp[kt] = pack8(*(const f32x4*)(xp + kt * 32),
                                *(const f32x4*)(xp + kt * 32 + 4));
        }

        // ---- final step: end-barrier per wv-cohort, then f32 finals ----
        if (s == T_STEPS - 1) {
            if (l == 0)
                __hip_atomic_store(flags + wv * 32 + wg, 1u,
                                   __ATOMIC_RELEASE, __HIP_MEMORY_SCOPE_AGENT);
            const uint32_t* fp = flags + wv * 32 + (l & 31);
            while (true) {
                uint32_t fvv = __hip_atomic_load(fp, __ATOMIC_RELAXED,
                                                 __HIP_MEMORY_SCOPE_AGENT);
                if (__all((int)(fvv >= 1u))) break;
                if (--budget < 0) break;       // deadlock escape
                __builtin_amdgcn_s_sleep(1);
            }
            float* outf = (float*)buf1;
#pragma unroll
            for (int p = 0; p < 2; ++p)
#pragma unroll
                for (int r = 0; r < 4; ++r)
                    if ((l & 12) == 0)
                        outf[(size_t)(orow0 + r) * 256 + 8 * wg + 4 * p + jj] = hv[p][r];
        }
    }
}

extern "C" void kernel_launch(void* const* d_in, const int* in_sizes, int n_in,
                              void* d_out, int out_size, void* d_ws, size_t ws_size,
                              hipStream_t stream) {
    const float* x    = (const float*)d_in[0];
    const float* W_ih = (const float*)d_in[1];
    const float* W_hh = (const float*)d_in[2];
    const float* b_ih = (const float*)d_in[3];
    const float* b_hh = (const float*)d_in[4];

    uint32_t* buf0  = (uint32_t*)d_ws;            // 16384 u32 = 64 KB
    uint32_t* flags = buf0 + 16384;               // 4*32 u32
    uint32_t* buf1  = (uint32_t*)d_out;           // 64 KB, doubles as output

    // zero tags/flags (graph-capture-safe async memsets)
    hipMemsetAsync(d_ws, 0, (16384 + 4 * 32) * sizeof(uint32_t), stream);
    hipMemsetAsync(d_out, 0, 16384 * sizeof(uint32_t), stream);

    lstm_tagged<<<dim3(NWG), dim3(256), 0, stream>>>(x, W_ih, W_hh, b_ih, b_hh,
                                                     buf0, buf1, flags);
}

// Round 16
// 15288.431 us; speedup vs baseline: 4.6114x; 2.5325x over previous
//
#include <hip/hip_runtime.h>
#include <hip/hip_bf16.h>
#include <stdint.h>

// LSTM: T=2048, B=64, I=256, H=256, gates 4H=1024, K = I+H = 512.
// 32 WGs x 256 threads = 128 independent waves. Wave (wg,wv) owns batch
// rows [16wv,+16) x h-cols [8wg,+8). Weights resident in VGPRs (128/lane).
// TAGGED exchange (R12-proven correct): h stored as u32 (bf16<<16 | step)
// into 2 rotating buffers (buf0=d_ws, buf1=d_out). Consumer issues ONE
// speculative wide read per step (tags self-verify freshness); on miss it
// polls the NARROW per-cohort flag line (R3/R5-proven) then re-reads once.
// Producers: tagged stores -> vmcnt(0) -> per-wave flag store (release).
// NBUF=2 safe: tag-check success at step s+1 implies global step-s done.
// All spins budget-capped. End: flag==2048 barrier gates f32 finals.

#define T_STEPS 2048
#define NWG 32

typedef float f32x4 __attribute__((ext_vector_type(4)));
typedef short bf16x8 __attribute__((ext_vector_type(8)));
typedef uint32_t u32x4 __attribute__((ext_vector_type(4)));

__device__ __forceinline__ unsigned short tobf(float f) {
    __hip_bfloat16 h = __float2bfloat16(f);
    return *reinterpret_cast<unsigned short*>(&h);
}

__device__ __forceinline__ bf16x8 pack8(f32x4 a, f32x4 b) {
    bf16x8 r;
    r[0] = (short)tobf(a[0]); r[1] = (short)tobf(a[1]);
    r[2] = (short)tobf(a[2]); r[3] = (short)tobf(a[3]);
    r[4] = (short)tobf(b[0]); r[5] = (short)tobf(b[1]);
    r[6] = (short)tobf(b[2]); r[7] = (short)tobf(b[3]);
    return r;
}

__device__ __forceinline__ float fast_sig(float x) {
    float e = __builtin_amdgcn_exp2f(-1.4426950408889634f * x);
    return __builtin_amdgcn_rcpf(1.0f + e);
}
__device__ __forceinline__ float fast_tanh(float x) {
    float xc = fminf(fmaxf(x, -15.0f), 15.0f);
    float e = __builtin_amdgcn_exp2f(2.8853900817779268f * xc);
    return (e - 1.0f) * __builtin_amdgcn_rcpf(e + 1.0f);
}

__global__ __launch_bounds__(256, 1)
void lstm_spec(const float* __restrict__ x,
               const float* __restrict__ W_ih,
               const float* __restrict__ W_hh,
               const float* __restrict__ b_ih,
               const float* __restrict__ b_hh,
               uint32_t* __restrict__ buf0,   // d_ws: [64][256] u32 tagged
               uint32_t* __restrict__ buf1,   // d_out: [64][256] u32 tagged / f32 finals
               uint32_t* __restrict__ flags)  // [4][32] u32 step flags
{
    const int wg   = blockIdx.x;     // 0..31
    const int tid  = threadIdx.x;    // 0..255
    const int wv   = tid >> 6;       // wave 0..3 = batch group
    const int l    = tid & 63;
    const int l15  = l & 15;
    const int lk   = l >> 4;         // 0..3
    const int gate = l15 >> 2;       // 0:i 1:f 2:g 3:o
    const int jj   = l15 & 3;

    int budget = 1 << 24;            // spin budget (deadlock escape)

    // ---- resident weight fragments: 2 N-groups x 16 ktiles of K=32 ----
    bf16x8 wf[2][16];
    float bias[2];
#pragma unroll
    for (int p = 0; p < 2; ++p) {
        const int grow = 256 * gate + 8 * wg + 4 * p + jj;
#pragma unroll
        for (int kt = 0; kt < 16; ++kt) {
            const float* src = (kt < 8)
                ? (W_ih + (size_t)grow * 256 + kt * 32 + lk * 8)
                : (W_hh + (size_t)grow * 256 + (kt - 8) * 32 + lk * 8);
            wf[p][kt] = pack8(*(const f32x4*)(src), *(const f32x4*)(src + 4));
        }
        bias[p] = b_ih[grow] + b_hh[grow];
    }

    const int arow = 16 * wv + l15;            // batch row for A fragments
    const float* xbase = x + (size_t)arow * 256 + lk * 8;

    float cst[2][4] = {{0.f,0.f,0.f,0.f},{0.f,0.f,0.f,0.f}};

    // ---- prologue: x_0 packed -> x-half(0) in aA/aB; then stage x_1 ----
    bf16x8 xsp[8];
#pragma unroll
    for (int kt = 0; kt < 8; ++kt)
        xsp[kt] = pack8(*(const f32x4*)(xbase + kt * 32),
                        *(const f32x4*)(xbase + kt * 32 + 4));

    f32x4 aA[2] = {{0.f,0.f,0.f,0.f},{0.f,0.f,0.f,0.f}};
    f32x4 aB[2] = {{0.f,0.f,0.f,0.f},{0.f,0.f,0.f,0.f}};
#pragma unroll
    for (int kt = 0; kt < 8; kt += 2)
#pragma unroll
        for (int p = 0; p < 2; ++p) {
            aA[p] = __builtin_amdgcn_mfma_f32_16x16x32_bf16(xsp[kt],     wf[p][kt],     aA[p], 0, 0, 0);
            aB[p] = __builtin_amdgcn_mfma_f32_16x16x32_bf16(xsp[kt + 1], wf[p][kt + 1], aB[p], 0, 0, 0);
        }
#pragma unroll
    for (int kt = 0; kt < 8; ++kt)
        xsp[kt] = pack8(*(const f32x4*)(xbase + 16384 + kt * 32),
                        *(const f32x4*)(xbase + 16384 + kt * 32 + 4));

    const uint32_t* mypollflag = flags + wv * 32 + (l & 31);
    uint32_t* myflag = flags + wv * 32 + wg;

    for (int s = 0; s < T_STEPS; ++s) {
        // ---- issue ONE speculative tagged wide read (u64 atomics, MALL) ----
        const uint32_t* rb = (s & 1) ? buf1 : buf0;
        const unsigned long long* hb64 =
            (const unsigned long long*)(rb + (size_t)arow * 256) + 4 * lk;
        unsigned long long hq[32];
#pragma unroll
        for (int kh = 0; kh < 8; ++kh)
#pragma unroll
            for (int i = 0; i < 4; ++i)
                hq[4 * kh + i] = __hip_atomic_load(hb64 + 16 * kh + i,
                                                   __ATOMIC_RELAXED, __HIP_MEMORY_SCOPE_AGENT);

        // ---- x-half(s+1) into acc2 while the read is in flight ----
        f32x4 aA2[2] = {{0.f,0.f,0.f,0.f},{0.f,0.f,0.f,0.f}};
        f32x4 aB2[2] = {{0.f,0.f,0.f,0.f},{0.f,0.f,0.f,0.f}};
        if (s + 1 < T_STEPS) {
#pragma unroll
            for (int kt = 0; kt < 8; kt += 2)
#pragma unroll
                for (int p = 0; p < 2; ++p) {
                    aA2[p] = __builtin_amdgcn_mfma_f32_16x16x32_bf16(xsp[kt],     wf[p][kt],     aA2[p], 0, 0, 0);
                    aB2[p] = __builtin_amdgcn_mfma_f32_16x16x32_bf16(xsp[kt + 1], wf[p][kt + 1], aB2[p], 0, 0, 0);
                }
        }
        __builtin_amdgcn_sched_barrier(0);

        // ---- tag verify; on miss: narrow flag wait + one wide re-read ----
        const unsigned long long tagpair =
            (unsigned long long)(uint32_t)s * 0x0000000100000001ull;
        const unsigned long long tmask = 0x0000FFFF0000FFFFull;
        {
            unsigned long long bad = 0;
#pragma unroll
            for (int i = 0; i < 32; ++i) bad |= (hq[i] ^ tagpair) & tmask;
            if (!__all(bad == 0ull)) {
                // narrow flag wait (proven coalesced 128B line poll)
                const uint32_t target = (uint32_t)s;
                while (true) {
                    uint32_t fv = __hip_atomic_load(mypollflag, __ATOMIC_RELAXED,
                                                    __HIP_MEMORY_SCOPE_AGENT);
                    if (__all((int)(fv >= target))) break;
                    if (--budget < 0) break;
                    __builtin_amdgcn_s_sleep(1);
                }
                // wide re-read (normally exactly once; budget-capped retry)
                while (true) {
#pragma unroll
                    for (int kh = 0; kh < 8; ++kh)
#pragma unroll
                        for (int i = 0; i < 4; ++i)
                            hq[4 * kh + i] = __hip_atomic_load(hb64 + 16 * kh + i,
                                                               __ATOMIC_RELAXED, __HIP_MEMORY_SCOPE_AGENT);
                    bad = 0;
#pragma unroll
                    for (int i = 0; i < 32; ++i) bad |= (hq[i] ^ tagpair) & tmask;
                    if (__all(bad == 0ull)) break;
                    if (--budget < 0) break;
                    __builtin_amdgcn_s_sleep(1);
                }
            }
        }

        // ---- unpack payloads -> h fragments; h-half MFMAs ----
#pragma unroll
        for (int kh = 0; kh < 8; ++kh) {
            u32x4 t;
#pragma unroll
            for (int i = 0; i < 4; ++i) {
                unsigned long long q = hq[4 * kh + i];
                t[i] = (((uint32_t)q) >> 16) | ((uint32_t)(q >> 32) & 0xFFFF0000u);
            }
            bf16x8 hf = __builtin_bit_cast(bf16x8, t);
#pragma unroll
            for (int p = 0; p < 2; ++p) {
                if (kh & 1) aB[p] = __builtin_amdgcn_mfma_f32_16x16x32_bf16(hf, wf[p][8 + kh], aB[p], 0, 0, 0);
                else        aA[p] = __builtin_amdgcn_mfma_f32_16x16x32_bf16(hf, wf[p][8 + kh], aA[p], 0, 0, 0);
            }
        }

        // ---- epilogue: gather i/f/g/o, update c, h ----
        const int orow0 = 16 * wv + 4 * lk;
        float hv[2][4];
#pragma unroll
        for (int p = 0; p < 2; ++p) {
#pragma unroll
            for (int r = 0; r < 4; ++r) {
                float vo  = aA[p][r] + aB[p][r] + bias[p];
                float v4  = __shfl_xor(vo, 4);
                float v8  = __shfl_xor(vo, 8);
                float v12 = __shfl_xor(vo, 12);
                float iv = (gate == 0) ? vo : ((gate == 1) ? v4 : ((gate == 2) ? v8 : v12));
                float fv = (gate == 1) ? vo : ((gate == 0) ? v4 : ((gate == 3) ? v8 : v12));
                float gv = (gate == 2) ? vo : ((gate == 3) ? v4 : ((gate == 0) ? v8 : v12));
                float ov = (gate == 3) ? vo : ((gate == 2) ? v4 : ((gate == 1) ? v8 : v12));
                float cn = fast_sig(fv) * cst[p][r] + fast_sig(iv) * fast_tanh(gv);
                cst[p][r] = cn;
                hv[p][r] = fast_sig(ov) * fast_tanh(cn);
            }
        }

        // ---- store tagged h_{s+1}; drain; per-wave flag release ----
        if (s + 1 < T_STEPS) {
            uint32_t* wb = ((s + 1) & 1) ? buf1 : buf0;
            const uint32_t tago = (uint32_t)(s + 1);
#pragma unroll
            for (int p = 0; p < 2; ++p)
#pragma unroll
                for (int r = 0; r < 4; ++r)
                    if ((l & 12) == 0) {   // gate==0 lanes: 16 lanes cover the tile
                        uint32_t word = ((uint32_t)tobf(hv[p][r]) << 16) | tago;
                        __hip_atomic_store(wb + (size_t)(orow0 + r) * 256
                                               + 8 * wg + 4 * p + jj,
                                           word, __ATOMIC_RELAXED, __HIP_MEMORY_SCOPE_AGENT);
                    }
            asm volatile("s_waitcnt vmcnt(0)" ::: "memory");   // stores visible
            if (l == 0)
                __hip_atomic_store(myflag, tago,
                                   __ATOMIC_RELEASE, __HIP_MEMORY_SCOPE_AGENT);
        }

        // ---- rotate accumulators; prefetch x_{s+2} ----
#pragma unroll
        for (int p = 0; p < 2; ++p) { aA[p] = aA2[p]; aB[p] = aB2[p]; }
        if (s + 2 < T_STEPS) {
            const float* xp = xbase + (size_t)(s + 2) * 16384;
#pragma unroll
            for (int kt = 0; kt < 8; ++kt)
                xsp[kt] = pack8(*(const f32x4*)(xp + kt * 32),
                                *(const f32x4*)(xp + kt * 32 + 4));
        }

        // ---- final step: flag=2048 barrier, then f32 finals into buf1 ----
        if (s == T_STEPS - 1) {
            if (l == 0)
                __hip_atomic_store(myflag, (uint32_t)T_STEPS,
                                   __ATOMIC_RELEASE, __HIP_MEMORY_SCOPE_AGENT);
            while (true) {
                uint32_t fvv = __hip_atomic_load(mypollflag, __ATOMIC_RELAXED,
                                                 __HIP_MEMORY_SCOPE_AGENT);
                if (__all((int)(fvv >= (uint32_t)T_STEPS))) break;
                if (--budget < 0) break;
                __builtin_amdgcn_s_sleep(1);
            }
            float* outf = (float*)buf1;
#pragma unroll
            for (int p = 0; p < 2; ++p)
#pragma unroll
                for (int r = 0; r < 4; ++r)
                    if ((l & 12) == 0)
                        outf[(size_t)(orow0 + r) * 256 + 8 * wg + 4 * p + jj] = hv[p][r];
        }
    }
}

extern "C" void kernel_launch(void* const* d_in, const int* in_sizes, int n_in,
                              void* d_out, int out_size, void* d_ws, size_t ws_size,
                              hipStream_t stream) {
    const float* x    = (const float*)d_in[0];
    const float* W_ih = (const float*)d_in[1];
    const float* W_hh = (const float*)d_in[2];
    const float* b_ih = (const float*)d_in[3];
    const float* b_hh = (const float*)d_in[4];

    uint32_t* buf0  = (uint32_t*)d_ws;            // 16384 u32 = 64 KB
    uint32_t* flags = buf0 + 16384;               // 4*32 u32
    uint32_t* buf1  = (uint32_t*)d_out;           // 64 KB, doubles as output

    // zero tags/flags (graph-capture-safe async memsets)
    hipMemsetAsync(d_ws, 0, (16384 + 4 * 32) * sizeof(uint32_t), stream);
    hipMemsetAsync(d_out, 0, 16384 * sizeof(uint32_t), stream);

    lstm_spec<<<dim3(NWG), dim3(256), 0, stream>>>(x, W_ih, W_hh, b_ih, b_hh,
                                                   buf0, buf1, flags);
}